// Round 1
// 298.172 us; speedup vs baseline: 1.0281x; 1.0281x over previous
//
#include <hip/hip_runtime.h>
#include <hip/hip_bf16.h>

typedef __attribute__((ext_vector_type(8))) short short8;
typedef __attribute__((ext_vector_type(4))) short short4v;
typedef __attribute__((ext_vector_type(4))) float f32x4;
typedef __attribute__((ext_vector_type(4))) float float4v;

#define S_LEN 2048
#define DMODEL 2048
#define N_HEADS 16
#define HEAD_DIM 128
#define NKT 32  // K-tiles of 64 across DMODEL

__device__ __forceinline__ float bf2f(__hip_bfloat16 b) { return __bfloat162float(b); }
__device__ __forceinline__ __hip_bfloat16 f2bf(float f) { return __float2bfloat16(f); }
__device__ __forceinline__ short bfs(float f) {
    union { __hip_bfloat16 b; short s; } x; x.b = __float2bfloat16(f); return x.s;
}
__device__ __forceinline__ float sbf(short s) {
    union { short s; __hip_bfloat16 b; } x; x.s = s; return __bfloat162float(x.b);
}

#if __has_builtin(__builtin_amdgcn_global_load_lds)
#define HAVE_ASYNC_LDS 1
#else
#define HAVE_ASYNC_LDS 0
#endif

// Stage 16B per lane into LDS. ldsbase must be wave-uniform; HW scatters lane i at base + 16*i.
__device__ __forceinline__ void stage16(const __hip_bfloat16* g, __hip_bfloat16* ldsbase, int lane) {
#if HAVE_ASYNC_LDS
    __builtin_amdgcn_global_load_lds(
        (const __attribute__((address_space(1))) unsigned int*)g,
        (__attribute__((address_space(3))) unsigned int*)ldsbase,
        16, 0, 0);
#else
    *(short8*)((char*)ldsbase + lane * 16) = *(const short8*)g;
#endif
}

// ---------------- prep: 4 weight transposes (f32->bf16, vectorized) + x conversion ----------------
// grid (32,32,5), 256 threads. z<4: 64x64 transpose tiles; z==4: x convert (16 elems/thread).
__global__ __launch_bounds__(256) void prep(const float* __restrict__ x,
                                            const float* __restrict__ w0,
                                            const float* __restrict__ w1,
                                            const float* __restrict__ w2,
                                            const float* __restrict__ w3,
                                            __hip_bfloat16* __restrict__ xb,
                                            __hip_bfloat16* __restrict__ o0,
                                            __hip_bfloat16* __restrict__ o1,
                                            __hip_bfloat16* __restrict__ o2,
                                            __hip_bfloat16* __restrict__ o3) {
    const int z = blockIdx.z;
    const int tid = threadIdx.x;
    if (z == 4) {
        size_t base = (((size_t)blockIdx.y * 32 + blockIdx.x) * 256 + tid) * 16;
        for (int i = 0; i < 4; ++i) {
            float4v v = *(const float4v*)(x + base + i * 4);
            short4v p;
            p.x = bfs(v.x); p.y = bfs(v.y); p.z = bfs(v.z); p.w = bfs(v.w);
            *(short4v*)((short*)xb + base + i * 4) = p;
        }
        return;
    }
    const float* in = (z == 0) ? w0 : (z == 1) ? w1 : (z == 2) ? w2 : w3;
    __hip_bfloat16* out = (z == 0) ? o0 : (z == 1) ? o1 : (z == 2) ? o2 : o3;
    __shared__ short tile[64][68];
    const int bx = blockIdx.x * 64;
    const int by = blockIdx.y * 64;
    const int c4 = (tid & 15) * 4;
    for (int rr = 0; rr < 4; ++rr) {
        int r = (tid >> 4) + rr * 16;
        float4v v = *(const float4v*)(in + (size_t)(by + r) * DMODEL + bx + c4);
        short4v p;
        p.x = bfs(v.x); p.y = bfs(v.y); p.z = bfs(v.z); p.w = bfs(v.w);
        *(short4v*)&tile[r][c4] = p;
    }
    __syncthreads();
    const int oc = tid >> 2;
    const int s0 = (tid & 3) * 16;
    short8 a, b;
    for (int i = 0; i < 8; ++i) ((short*)&a)[i] = tile[s0 + i][oc];
    for (int i = 0; i < 8; ++i) ((short*)&b)[i] = tile[s0 + 8 + i][oc];
    *(short8*)((short*)out + (size_t)(bx + oc) * DMODEL + by + s0) = a;
    *(short8*)((short*)out + (size_t)(bx + oc) * DMODEL + by + s0 + 8) = b;
}

// ---------------- 8-phase 256x256 QKV GEMM (T2 swizzle + T3/T4 counted vmcnt + T5 setprio) ----------
// grid (24,8): blockIdx.x>>3 selects {Q,K,V}, &7 = n-tile. 512 threads = 8 waves (2M x 4N),
// per-wave 128x64 output. BK=64, LDS 128 KiB double-buffered, full K (no split-K).
// RoPE fused into Q/K epilogue; V stored transposed. Replaces gemm_qkv_sk + reduce_rope.

#define CFENCE asm volatile("" ::: "memory")
#define BARRIER do { CFENCE; __builtin_amdgcn_s_barrier(); CFENCE; } while (0)
#define WAIT_LGKM0 asm volatile("s_waitcnt lgkmcnt(0)" ::: "memory")
#define WAIT_VM(n) asm volatile("s_waitcnt vmcnt(" #n ")" ::: "memory")

// LDS map (shorts): A half-tile (buf,half) at (buf*2+half)*8192 ; B at 32768 + (buf*2+half)*8192.
// Half-tile = 128 rows x 64 cols bf16 (128B rows), linear. Swizzle is logical:
// LDS granule gL of row r holds global k-granule gL ^ (r&7)  (granule = 8 bf16 = 16B).
// Staged with linear LDS dest + pre-swizzled global source (rule: both-sides-or-neither).

#define STAGE_A8(buf, half, kt) do {                                                        \
    const __hip_bfloat16* gpA_ = A + (size_t)(m0 + (half) * 128 + wave * 16 + rsel) * DMODEL \
                                 + (kt) * 64 + gsrc;                                        \
    __hip_bfloat16* lpA_ = (__hip_bfloat16*)(smem + ((buf) * 2 + (half)) * 8192 + wave * 1024); \
    stage16(gpA_, lpA_, lane);                                                              \
    stage16(gpA_ + (size_t)8 * DMODEL, lpA_ + 512, lane);                                   \
} while (0)

#define STAGE_B8(buf, half, kt) do {                                                        \
    const __hip_bfloat16* gpB_ = Bt + (size_t)(n0 + (half) * 128 + wave * 16 + rsel) * DMODEL \
                                 + (kt) * 64 + gsrc;                                        \
    __hip_bfloat16* lpB_ = (__hip_bfloat16*)(smem + 32768 + ((buf) * 2 + (half)) * 8192 + wave * 1024); \
    stage16(gpB_, lpB_, lane);                                                              \
    stage16(gpB_ + (size_t)8 * DMODEL, lpB_ + 512, lane);                                   \
} while (0)

#define LDA4(buf, mb) do {                                                                  \
    const char* ab_ = (const char*)(smem + ((buf) * 2 + wr) * 8192);                        \
    _Pragma("unroll")                                                                       \
    for (int mt_ = 0; mt_ < 4; ++mt_) {                                                     \
        const int rowL_ = ((mb) + mt_) * 16 + lane15;                                       \
        const int r7_ = rowL_ & 7;                                                          \
        af[(mb) + mt_][0] = *(const short8*)(ab_ + rowL_ * 128 + ((quad ^ r7_) * 16));      \
        af[(mb) + mt_][1] = *(const short8*)(ab_ + rowL_ * 128 + (((4 + quad) ^ r7_) * 16));\
    }                                                                                       \
} while (0)

#define LDB2(buf, nb) do {                                                                  \
    const char* bb_ = (const char*)(smem + 32768 + ((buf) * 2 + hb) * 8192);                \
    _Pragma("unroll")                                                                       \
    for (int nt_ = 0; nt_ < 2; ++nt_) {                                                     \
        const int rowL_ = wc1 * 64 + ((nb) + nt_) * 16 + lane15;                            \
        const int r7_ = rowL_ & 7;                                                          \
        bfr[nt_][0] = *(const short8*)(bb_ + rowL_ * 128 + ((quad ^ r7_) * 16));            \
        bfr[nt_][1] = *(const short8*)(bb_ + rowL_ * 128 + (((4 + quad) ^ r7_) * 16));      \
    }                                                                                       \
} while (0)

#define MFMAQ(mb, nb) do {                                                                  \
    _Pragma("unroll")                                                                       \
    for (int mt_ = 0; mt_ < 4; ++mt_) {                                                     \
        _Pragma("unroll")                                                                   \
        for (int nt_ = 0; nt_ < 2; ++nt_) {                                                 \
            acc[(mb) + mt_][(nb) + nt_] = __builtin_amdgcn_mfma_f32_16x16x32_bf16(          \
                af[(mb) + mt_][0], bfr[nt_][0], acc[(mb) + mt_][(nb) + nt_], 0, 0, 0);      \
            acc[(mb) + mt_][(nb) + nt_] = __builtin_amdgcn_mfma_f32_16x16x32_bf16(          \
                af[(mb) + mt_][1], bfr[nt_][1], acc[(mb) + mt_][(nb) + nt_], 0, 0, 0);      \
        }                                                                                   \
    }                                                                                       \
} while (0)

// Group g (one K-tile): 4 phases. Stages: B halves of (g+1) at p1/p2 into nxt buf,
// A halves of (g+2) at p3/p4 into cur buf (A region of cur is dead after p2's reads).
// vmcnt(4) once per group keeps A(g+2) (2 half-tiles) in flight across the boundary;
// the following barrier makes residency of K-tile g+1 block-wide (symmetric schedule).
#define GROUP(g, cur, nxt) do {                                                             \
    const int g_ = (g);                                                                     \
    const bool stB_ = (g_ + 1 < NKT);                                                       \
    const bool stA_ = (g_ + 2 < NKT);                                                       \
    /* phase 1: C-quadrant (m0-3 x n0-1) */                                                 \
    LDA4(cur, 0); LDB2(cur, 0);                                                             \
    if (stB_) STAGE_B8(nxt, 0, g_ + 1);                                                     \
    BARRIER; WAIT_LGKM0;                                                                    \
    __builtin_amdgcn_s_setprio(1); MFMAQ(0, 0); __builtin_amdgcn_s_setprio(0);              \
    BARRIER;                                                                                \
    /* phase 2: (m4-7 x n0-1) */                                                            \
    LDA4(cur, 4);                                                                           \
    if (stB_) STAGE_B8(nxt, 1, g_ + 1);                                                     \
    BARRIER; WAIT_LGKM0;                                                                    \
    __builtin_amdgcn_s_setprio(1); MFMAQ(4, 0); __builtin_amdgcn_s_setprio(0);              \
    BARRIER;                                                                                \
    /* phase 3: (m0-3 x n2-3) */                                                            \
    LDB2(cur, 2);                                                                           \
    if (stA_) STAGE_A8(cur, 0, g_ + 2);                                                     \
    BARRIER; WAIT_LGKM0;                                                                    \
    __builtin_amdgcn_s_setprio(1); MFMAQ(0, 2); __builtin_amdgcn_s_setprio(0);              \
    BARRIER;                                                                                \
    /* phase 4: (m4-7 x n2-3) */                                                            \
    if (stA_) STAGE_A8(cur, 1, g_ + 2);                                                     \
    BARRIER;                                                                                \
    __builtin_amdgcn_s_setprio(1); MFMAQ(4, 2); __builtin_amdgcn_s_setprio(0);              \
    if (stA_) { WAIT_VM(4); } else if (stB_) { WAIT_VM(0); }                                \
    BARRIER;                                                                                \
} while (0)

__global__ __launch_bounds__(512, 2) void gemm_qkv_8ph(const __hip_bfloat16* __restrict__ A,
                                                       const __hip_bfloat16* __restrict__ Bq,
                                                       const __hip_bfloat16* __restrict__ Bk,
                                                       const __hip_bfloat16* __restrict__ Bv,
                                                       __hip_bfloat16* __restrict__ Cq,
                                                       __hip_bfloat16* __restrict__ Ck,
                                                       __hip_bfloat16* __restrict__ Cvt,
                                                       const float* __restrict__ fc,
                                                       const float* __restrict__ fs) {
    __shared__ alignas(16) short smem[65536];  // 128 KiB: A 64K + B 64K, each 2buf x 2half x 16KB

    const int tid = threadIdx.x;
    const int wave = tid >> 6;
    const int lane = tid & 63;
    const int lane15 = lane & 15;
    const int quad = lane >> 4;
    const int wr = wave >> 2;      // wave row 0..1  (A half = wr)
    const int wc = wave & 3;       // wave col 0..3
    const int wc1 = wc & 1;
    const int hb = wc >> 1;        // B half consumed by this wave
    const int rsel = lane >> 3;                    // staging: row-within-chunk
    const int gsrc = ((lane & 7) ^ rsel) * 8;      // staging: pre-swizzled source granule

    const int which = blockIdx.x >> 3;
    const int n0 = (blockIdx.x & 7) * 256;
    const int m0 = blockIdx.y * 256;
    const __hip_bfloat16* Bt = (which == 0) ? Bq : (which == 1) ? Bk : Bv;

    short8 af[8][2];
    short8 bfr[2][2];
    f32x4 acc[8][4];

    // prologue: all of K-tile 0 into buf0 (oldest 8 loads), then A halves of K-tile 1 into buf1.
    STAGE_A8(0, 0, 0);
    STAGE_B8(0, 0, 0);
    STAGE_A8(0, 1, 0);
    STAGE_B8(0, 1, 0);
    STAGE_A8(1, 0, 1);
    STAGE_A8(1, 1, 1);
#pragma unroll
    for (int i = 0; i < 8; ++i)
#pragma unroll
        for (int j = 0; j < 4; ++j)
            acc[i][j] = {0.f, 0.f, 0.f, 0.f};
    WAIT_VM(4);   // K-tile 0 resident; A(1) still in flight
    BARRIER;

#pragma unroll 1
    for (int g = 0; g < NKT; g += 2) {
        GROUP(g, 0, 1);
        GROUP(g + 1, 1, 0);
    }

    // epilogue: acc[mt][nt][i] -> row = m0 + wr*128 + mt*16 + quad*4 + i,
    //                             col = n0 + wc*64 + nt*16 + lane15
    if (which < 2) {
        __hip_bfloat16* C = (which == 0) ? Cq : Ck;
#pragma unroll
        for (int mt = 0; mt < 8; ++mt)
#pragma unroll
            for (int nt = 0; nt < 4; ++nt) {
                int col = n0 + wc * 64 + nt * 16 + lane15;
                int j = (col & 127) >> 1;
                bool odd = col & 1;
#pragma unroll
                for (int i = 0; i < 4; ++i) {
                    int row = m0 + wr * 128 + mt * 16 + quad * 4 + i;
                    float v = acc[mt][nt][i];
                    float p = __shfl_xor(v, 1, 64);
                    float c = fc[row * 64 + j];
                    float sn = fs[row * 64 + j];
                    float r = odd ? (p * sn + v * c) : (v * c - p * sn);
                    C[(size_t)row * DMODEL + col] = f2bf(r);
                }
            }
    } else {
#pragma unroll
        for (int mt = 0; mt < 8; ++mt) {
            int rowbase = m0 + wr * 128 + mt * 16 + quad * 4;
#pragma unroll
            for (int nt = 0; nt < 4; ++nt) {
                int col = n0 + wc * 64 + nt * 16 + lane15;
                short4v pk;
                pk.x = bfs(acc[mt][nt][0]);
                pk.y = bfs(acc[mt][nt][1]);
                pk.z = bfs(acc[mt][nt][2]);
                pk.w = bfs(acc[mt][nt][3]);
                *(short4v*)((short*)Cvt + (size_t)col * S_LEN + rowbase) = pk;
            }
        }
    }
}

// ---------------- final GEMM: out(f32) = A * Bt^T, 128x64 tiles, K-pair staging ----------------
__global__ __launch_bounds__(256) void gemm_out(const __hip_bfloat16* __restrict__ A,
                                                const __hip_bfloat16* __restrict__ Bt,
                                                float* __restrict__ C) {
    __shared__ alignas(16) __hip_bfloat16 As[2][128 * 32];
    __shared__ alignas(16) __hip_bfloat16 Bs[2][64 * 32];
    const int tid = threadIdx.x;
    const int wave = tid >> 6;
    const int lane = tid & 63;
    const int lane15 = lane & 15;
    const int quad = lane >> 4;
    const int m0 = blockIdx.y * 128;
    const int n0 = blockIdx.x * 64;
    const int wm = (wave >> 1) * 64;
    const int wn = (wave & 1) * 32;
    f32x4 acc[4][2];
    for (int i = 0; i < 4; ++i)
        for (int j = 0; j < 2; ++j)
            acc[i][j] = {0.f, 0.f, 0.f, 0.f};
    const int rA = lane >> 2;
    const int cA = (lane & 3) * 8;
    for (int k0 = 0; k0 < DMODEL; k0 += 64) {
        __syncthreads();
        for (int h = 0; h < 2; ++h) {
            int kk = k0 + h * 32;
            for (int c = 0; c < 3; ++c) {
                int chunk = wave * 3 + c;
                if (chunk < 8) {
                    int r = chunk * 16 + rA;
                    stage16(A + (size_t)(m0 + r) * DMODEL + kk + cA, As[h] + chunk * 512, lane);
                } else {
                    int r = (chunk - 8) * 16 + rA;
                    stage16(Bt + (size_t)(n0 + r) * DMODEL + kk + cA, Bs[h] + (chunk - 8) * 512, lane);
                }
            }
        }
#if HAVE_ASYNC_LDS
        asm volatile("s_waitcnt vmcnt(0)" ::: "memory");
#endif
        __syncthreads();
        for (int h = 0; h < 2; ++h) {
            short8 af[4], bfr[2];
            for (int mt = 0; mt < 4; ++mt)
                af[mt] = *(const short8*)(As[h] + (wm + mt * 16 + lane15) * 32 + quad * 8);
            for (int nt = 0; nt < 2; ++nt)
                bfr[nt] = *(const short8*)(Bs[h] + (wn + nt * 16 + lane15) * 32 + quad * 8);
            for (int mt = 0; mt < 4; ++mt)
                for (int nt = 0; nt < 2; ++nt)
                    acc[mt][nt] = __builtin_amdgcn_mfma_f32_16x16x32_bf16(af[mt], bfr[nt], acc[mt][nt], 0, 0, 0);
        }
    }
    for (int mt = 0; mt < 4; ++mt)
        for (int nt = 0; nt < 2; ++nt)
            for (int i = 0; i < 4; ++i) {
                int row = m0 + wm + mt * 16 + quad * 4 + i;
                int col = n0 + wn + nt * 16 + lane15;
                C[(size_t)row * DMODEL + col] = acc[mt][nt][i];
            }
}

// ---------------- flash attention (LDS-shared K/V, fixed-base softmax) ----------------
__global__ __launch_bounds__(256) void flash_attn(const __hip_bfloat16* __restrict__ Q,
                                                  const __hip_bfloat16* __restrict__ Kb,
                                                  const __hip_bfloat16* __restrict__ Vt,
                                                  __hip_bfloat16* __restrict__ O) {
    __shared__ alignas(16) short Ks[32][136];
    __shared__ alignas(16) short Vs[128][40];
    __shared__ alignas(16) short Pl[4][16][40];
    const int tid = threadIdx.x;
    const int wave = tid >> 6;
    const int lane = tid & 63;
    const int lane15 = lane & 15;
    const int quad = lane >> 4;
    const int bx = blockIdx.x;                   // 0..511
    const int u = bx & 255;
    const int head = u & 15;
    const int qp = u >> 4;
    const int qb = (bx < 256) ? (31 - qp) : qp;  // complementary pairing
    const int qbase = qb * 64;
    const int q0w = qbase + wave * 16;
    const int nkt = 2 * qb + 2;
    const float K1 = 0.08838834764831845f * (1.0f / 25.0f);

    const __hip_bfloat16* Qh = Q + (size_t)q0w * DMODEL + head * HEAD_DIM;
    short8 qf[4];
    for (int kk = 0; kk < 4; ++kk)
        qf[kk] = *(const short8*)(Qh + (size_t)lane15 * DMODEL + kk * 32 + quad * 8);

    f32x4 acc[8];
    for (int i = 0; i < 8; ++i) acc[i] = {0.f, 0.f, 0.f, 0.f};
    float lpart[4] = {0.f, 0.f, 0.f, 0.f};

    const int krow = tid >> 3, kcol = (tid & 7) * 16;
    const int vrow = tid >> 1, vcol = (tid & 1) * 16;
    const __hip_bfloat16* Kg = Kb + (size_t)krow * DMODEL + head * HEAD_DIM + kcol;
    const __hip_bfloat16* Vg = Vt + (size_t)(head * HEAD_DIM + vrow) * S_LEN + vcol;

    short8 gk0 = *(const short8*)(Kg);
    short8 gk1 = *(const short8*)(Kg + 8);
    short8 gv0 = *(const short8*)(Vg);
    short8 gv1 = *(const short8*)(Vg + 8);

    for (int kt = 0; kt < nkt; ++kt) {
        const int kb = kt * 32;
        __syncthreads();
        *(short8*)&Ks[krow][kcol] = gk0;
        *(short8*)&Ks[krow][kcol + 8] = gk1;
        *(short8*)&Vs[vrow][vcol] = gv0;
        *(short8*)&Vs[vrow][vcol + 8] = gv1;
        __syncthreads();

        if (kt + 1 < nkt) {
            const __hip_bfloat16* Kg2 = Kg + (size_t)(kb + 32) * DMODEL;
            const __hip_bfloat16* Vg2 = Vg + kb + 32;
            gk0 = *(const short8*)(Kg2);
            gk1 = *(const short8*)(Kg2 + 8);
            gv0 = *(const short8*)(Vg2);
            gv1 = *(const short8*)(Vg2 + 8);
        }

        if (kb <= q0w + 15) {
            f32x4 sc[2];
            sc[0] = {0.f, 0.f, 0.f, 0.f};
            sc[1] = {0.f, 0.f, 0.f, 0.f};
            for (int c = 0; c < 2; ++c)
                for (int kk = 0; kk < 4; ++kk) {
                    short8 kf = *(const short8*)&Ks[c * 16 + lane15][kk * 32 + quad * 8];
                    sc[c] = __builtin_amdgcn_mfma_f32_16x16x32_bf16(qf[kk], kf, sc[c], 0, 0, 0);
                }

            const bool masked = (kb + 31 > q0w);
            const int key0 = kb + lane15;
            const int key1 = kb + 16 + lane15;
            for (int i = 0; i < 4; ++i) {
                float e0 = __expf(sc[0][i] * K1);
                float e1 = __expf(sc[1][i] * K1);
                float c0 = __builtin_fmaf(-100.0f, __builtin_amdgcn_rcpf(e0 + 1.0f), 40.0f);
                float c1 = __builtin_fmaf(-100.0f, __builtin_amdgcn_rcpf(e1 + 1.0f), 40.0f);
                float p0 = __expf(c0);
                float p1 = __expf(c1);
                if (masked) {
                    int q = q0w + quad * 4 + i;
                    if (key0 > q) p0 = 0.f;
                    if (key1 > q) p1 = 0.f;
                }
                short b0 = bfs(p0), b1 = bfs(p1);
                lpart[i] += sbf(b0) + sbf(b1);
                Pl[wave][quad * 4 + i][lane15] = b0;
                Pl[wave][quad * 4 + i][16 + lane15] = b1;
            }
            asm volatile("s_waitcnt lgkmcnt(0)" ::: "memory");
            short8 pf = *(const short8*)&Pl[wave][lane15][quad * 8];
            asm volatile("" ::: "memory");
            for (int nt = 0; nt < 8; ++nt) {
                short8 vf = *(const short8*)&Vs[nt * 16 + lane15][quad * 8];
                acc[nt] = __builtin_amdgcn_mfma_f32_16x16x32_bf16(pf, vf, acc[nt], 0, 0, 0);
            }
        }
    }

    for (int i = 0; i < 4; ++i) {
        float l = lpart[i];
        l += __shfl_xor(l, 1, 64);
        l += __shfl_xor(l, 2, 64);
        l += __shfl_xor(l, 4, 64);
        l += __shfl_xor(l, 8, 64);
        float inv = 1.0f / l;
        int row = q0w + quad * 4 + i;
        for (int nt = 0; nt < 8; ++nt) {
            int col = head * HEAD_DIM + nt * 16 + lane15;
            O[(size_t)row * DMODEL + col] = f2bf(acc[nt][i] * inv);
        }
    }
}

extern "C" void kernel_launch(void* const* d_in, const int* in_sizes, int n_in,
                              void* d_out, int out_size, void* d_ws, size_t ws_size,
                              hipStream_t stream) {
    const float* x  = (const float*)d_in[0];
    const float* wq = (const float*)d_in[1];
    const float* wk = (const float*)d_in[2];
    const float* wv = (const float*)d_in[3];
    const float* wo = (const float*)d_in[4];
    const float* fc = (const float*)d_in[5];
    const float* fs = (const float*)d_in[6];
    float* out = (float*)d_out;

    char* ws = (char*)d_ws;
    const size_t MB8 = (size_t)2048 * 2048 * sizeof(__hip_bfloat16);
    __hip_bfloat16* wq_t = (__hip_bfloat16*)(ws + 0 * MB8);
    __hip_bfloat16* wk_t = (__hip_bfloat16*)(ws + 1 * MB8);
    __hip_bfloat16* wv_t = (__hip_bfloat16*)(ws + 2 * MB8);
    __hip_bfloat16* wo_t = (__hip_bfloat16*)(ws + 3 * MB8);
    __hip_bfloat16* s4   = (__hip_bfloat16*)(ws + 4 * MB8);
    __hip_bfloat16* s5   = (__hip_bfloat16*)(ws + 5 * MB8);
    __hip_bfloat16* s6   = (__hip_bfloat16*)(ws + 6 * MB8);
    __hip_bfloat16* x_bf = (__hip_bfloat16*)d_out;  // dead before final GEMM writes d_out

    prep<<<dim3(32, 32, 5), 256, 0, stream>>>(x, wq, wk, wv, wo, x_bf, wq_t, wk_t, wv_t, wo_t);

    // Fused QKV: Q->s4 (roped), K->s5 (roped), V^T->s6. No reduce pass.
    gemm_qkv_8ph<<<dim3(24, 8), 512, 0, stream>>>(x_bf, wq_t, wk_t, wv_t, s4, s5, s6, fc, fs);

    // attn -> wq_t (dead after QKV GEMM)
    flash_attn<<<512, 256, 0, stream>>>(s4, s5, s6, wq_t);
    gemm_out<<<dim3(32, 16), 256, 0, stream>>>(wq_t, wo_t, out);
}

// Round 2
// 292.538 us; speedup vs baseline: 1.0479x; 1.0193x over previous
//
#include <hip/hip_runtime.h>
#include <hip/hip_bf16.h>

typedef __attribute__((ext_vector_type(8))) short short8;
typedef __attribute__((ext_vector_type(4))) short short4v;
typedef __attribute__((ext_vector_type(4))) float f32x4;
typedef __attribute__((ext_vector_type(4))) float float4v;

#define S_LEN 2048
#define DMODEL 2048
#define N_HEADS 16
#define HEAD_DIM 128
#define NKT 32  // K-tiles of 64 across DMODEL

__device__ __forceinline__ float bf2f(__hip_bfloat16 b) { return __bfloat162float(b); }
__device__ __forceinline__ __hip_bfloat16 f2bf(float f) { return __float2bfloat16(f); }
__device__ __forceinline__ short bfs(float f) {
    union { __hip_bfloat16 b; short s; } x; x.b = __float2bfloat16(f); return x.s;
}
__device__ __forceinline__ float sbf(short s) {
    union { short s; __hip_bfloat16 b; } x; x.s = s; return __bfloat162float(x.b);
}

#if __has_builtin(__builtin_amdgcn_global_load_lds)
#define HAVE_ASYNC_LDS 1
#else
#define HAVE_ASYNC_LDS 0
#endif

// Stage 16B per lane into LDS. ldsbase must be wave-uniform; HW scatters lane i at base + 16*i.
__device__ __forceinline__ void stage16(const __hip_bfloat16* g, __hip_bfloat16* ldsbase, int lane) {
#if HAVE_ASYNC_LDS
    __builtin_amdgcn_global_load_lds(
        (const __attribute__((address_space(1))) unsigned int*)g,
        (__attribute__((address_space(3))) unsigned int*)ldsbase,
        16, 0, 0);
#else
    *(short8*)((char*)ldsbase + lane * 16) = *(const short8*)g;
#endif
}

// ---------------- prep: 4 weight transposes (f32->bf16, vectorized) + x conversion ----------------
// grid (32,32,5), 256 threads. z<4: 64x64 transpose tiles; z==4: x convert (16 elems/thread).
__global__ __launch_bounds__(256) void prep(const float* __restrict__ x,
                                            const float* __restrict__ w0,
                                            const float* __restrict__ w1,
                                            const float* __restrict__ w2,
                                            const float* __restrict__ w3,
                                            __hip_bfloat16* __restrict__ xb,
                                            __hip_bfloat16* __restrict__ o0,
                                            __hip_bfloat16* __restrict__ o1,
                                            __hip_bfloat16* __restrict__ o2,
                                            __hip_bfloat16* __restrict__ o3) {
    const int z = blockIdx.z;
    const int tid = threadIdx.x;
    if (z == 4) {
        size_t base = (((size_t)blockIdx.y * 32 + blockIdx.x) * 256 + tid) * 16;
        for (int i = 0; i < 4; ++i) {
            float4v v = *(const float4v*)(x + base + i * 4);
            short4v p;
            p.x = bfs(v.x); p.y = bfs(v.y); p.z = bfs(v.z); p.w = bfs(v.w);
            *(short4v*)((short*)xb + base + i * 4) = p;
        }
        return;
    }
    const float* in = (z == 0) ? w0 : (z == 1) ? w1 : (z == 2) ? w2 : w3;
    __hip_bfloat16* out = (z == 0) ? o0 : (z == 1) ? o1 : (z == 2) ? o2 : o3;
    __shared__ short tile[64][68];
    const int bx = blockIdx.x * 64;
    const int by = blockIdx.y * 64;
    const int c4 = (tid & 15) * 4;
    for (int rr = 0; rr < 4; ++rr) {
        int r = (tid >> 4) + rr * 16;
        float4v v = *(const float4v*)(in + (size_t)(by + r) * DMODEL + bx + c4);
        short4v p;
        p.x = bfs(v.x); p.y = bfs(v.y); p.z = bfs(v.z); p.w = bfs(v.w);
        *(short4v*)&tile[r][c4] = p;
    }
    __syncthreads();
    const int oc = tid >> 2;
    const int s0 = (tid & 3) * 16;
    short8 a, b;
    for (int i = 0; i < 8; ++i) ((short*)&a)[i] = tile[s0 + i][oc];
    for (int i = 0; i < 8; ++i) ((short*)&b)[i] = tile[s0 + 8 + i][oc];
    *(short8*)((short*)out + (size_t)(bx + oc) * DMODEL + by + s0) = a;
    *(short8*)((short*)out + (size_t)(bx + oc) * DMODEL + by + s0 + 8) = b;
}

// ---------------- 256x256 QKV GEMM, 2-barrier groups with counted waits ----------------
// grid (24,8): blockIdx.x>>3 selects {Q,K,V}, &7 = n-tile. 512 threads = 8 waves (2M x 4N),
// per-wave 128x64 output. BK=64, LDS 128 KiB double-buffered.
// Per K-tile group: issue ALL 24 ds_read_b128 at top (compiler emits counted lgkmcnt before
// each consuming MFMA -> LDS stream overlaps matrix stream), stage B(g+1) at top,
// ONE mid lgkmcnt(0)+barrier (A-region overwrite hazard), stage A(g+2), Q3/Q4 MFMAs,
// vmcnt(4) (A(g+2) stays in flight across the boundary), barrier. 2 barriers/K-tile vs 8.
// RoPE fused into Q/K epilogue; V stored transposed.

#define CFENCE asm volatile("" ::: "memory")
#define BARRIER do { CFENCE; __builtin_amdgcn_s_barrier(); CFENCE; } while (0)
#define WAIT_LGKM0 asm volatile("s_waitcnt lgkmcnt(0)" ::: "memory")
#define WAIT_VM(n) asm volatile("s_waitcnt vmcnt(" #n ")" ::: "memory")

// LDS map (shorts): A half-tile (buf,half) at (buf*2+half)*8192 ; B at 32768 + (buf*2+half)*8192.
// Half-tile = 128 rows x 64 cols bf16 (128B rows), linear. Swizzle is logical:
// LDS granule gL of row r holds global k-granule gL ^ (r&7)  (granule = 8 bf16 = 16B).
// Staged with linear LDS dest + pre-swizzled global source (rule: both-sides-or-neither).

#define STAGE_A8(buf, half, kt) do {                                                        \
    const __hip_bfloat16* gpA_ = A + (size_t)(m0 + (half) * 128 + wave * 16 + rsel) * DMODEL \
                                 + (kt) * 64 + gsrc;                                        \
    __hip_bfloat16* lpA_ = (__hip_bfloat16*)(smem + ((buf) * 2 + (half)) * 8192 + wave * 1024); \
    stage16(gpA_, lpA_, lane);                                                              \
    stage16(gpA_ + (size_t)8 * DMODEL, lpA_ + 512, lane);                                   \
} while (0)

#define STAGE_B8(buf, half, kt) do {                                                        \
    const __hip_bfloat16* gpB_ = Bt + (size_t)(n0 + (half) * 128 + wave * 16 + rsel) * DMODEL \
                                 + (kt) * 64 + gsrc;                                        \
    __hip_bfloat16* lpB_ = (__hip_bfloat16*)(smem + 32768 + ((buf) * 2 + (half)) * 8192 + wave * 1024); \
    stage16(gpB_, lpB_, lane);                                                              \
    stage16(gpB_ + (size_t)8 * DMODEL, lpB_ + 512, lane);                                   \
} while (0)

// Read ALL A fragments of the wave's half (16 x ds_read_b128, conflict-free via XOR swizzle).
#define LDA_ALL(buf) do {                                                                   \
    const char* ab_ = (const char*)(smem + ((buf) * 2 + wr) * 8192);                        \
    _Pragma("unroll")                                                                       \
    for (int mt_ = 0; mt_ < 8; ++mt_) {                                                     \
        const int rowL_ = mt_ * 16 + lane15;                                                \
        const int r7_ = rowL_ & 7;                                                          \
        af[mt_][0] = *(const short8*)(ab_ + rowL_ * 128 + ((quad ^ r7_) * 16));             \
        af[mt_][1] = *(const short8*)(ab_ + rowL_ * 128 + (((4 + quad) ^ r7_) * 16));       \
    }                                                                                       \
} while (0)

// Read ALL B fragments for the wave's 64-col slice (8 x ds_read_b128).
#define LDB_ALL(buf) do {                                                                   \
    const char* bb_ = (const char*)(smem + 32768 + ((buf) * 2 + hb) * 8192);                \
    _Pragma("unroll")                                                                       \
    for (int nt_ = 0; nt_ < 4; ++nt_) {                                                     \
        const int rowL_ = wc1 * 64 + nt_ * 16 + lane15;                                     \
        const int r7_ = rowL_ & 7;                                                          \
        bfr[nt_][0] = *(const short8*)(bb_ + rowL_ * 128 + ((quad ^ r7_) * 16));            \
        bfr[nt_][1] = *(const short8*)(bb_ + rowL_ * 128 + (((4 + quad) ^ r7_) * 16));      \
    }                                                                                       \
} while (0)

#define MFMAQ(mb, nb) do {                                                                  \
    _Pragma("unroll")                                                                       \
    for (int mt_ = 0; mt_ < 4; ++mt_) {                                                     \
        _Pragma("unroll")                                                                   \
        for (int nt_ = 0; nt_ < 2; ++nt_) {                                                 \
            acc[(mb) + mt_][(nb) + nt_] = __builtin_amdgcn_mfma_f32_16x16x32_bf16(          \
                af[(mb) + mt_][0], bfr[(nb) + nt_][0], acc[(mb) + mt_][(nb) + nt_], 0, 0, 0); \
            acc[(mb) + mt_][(nb) + nt_] = __builtin_amdgcn_mfma_f32_16x16x32_bf16(          \
                af[(mb) + mt_][1], bfr[(nb) + nt_][1], acc[(mb) + mt_][(nb) + nt_], 0, 0, 0); \
        }                                                                                   \
    }                                                                                       \
} while (0)

// One K-tile group, 2 barriers. Entered right after the boundary barrier with:
//   cur = K-tile g fully resident; A(g+1) in flight into nxt.A.
#define GROUP(g, cur, nxt) do {                                                             \
    const int g_ = (g);                                                                     \
    const bool stB_ = (g_ + 1 < NKT);                                                       \
    const bool stA_ = (g_ + 2 < NKT);                                                       \
    LDA_ALL(cur);                                                                           \
    LDB_ALL(cur);                                                                           \
    if (stB_) { STAGE_B8(nxt, 0, g_ + 1); STAGE_B8(nxt, 1, g_ + 1); }                       \
    __builtin_amdgcn_s_setprio(1);                                                          \
    MFMAQ(0, 0); MFMAQ(4, 0);                                                               \
    __builtin_amdgcn_s_setprio(0);                                                          \
    WAIT_LGKM0;  /* all 24 reads of cur complete for this wave */                           \
    BARRIER;     /* block-wide: cur.A fully consumed -> safe to overwrite */                \
    if (stA_) { STAGE_A8(cur, 0, g_ + 2); STAGE_A8(cur, 1, g_ + 2); }                       \
    __builtin_amdgcn_s_setprio(1);                                                          \
    MFMAQ(0, 2); MFMAQ(4, 2);                                                               \
    __builtin_amdgcn_s_setprio(0);                                                          \
    if (stA_) { WAIT_VM(4); }          /* A(g+1),B(g+1) done; A(g+2) stays in flight */     \
    else if (stB_) { WAIT_VM(0); }     /* tail: no A-stage issued, must drain B(g+1) */     \
    BARRIER;                                                                                \
} while (0)

__global__ __launch_bounds__(512, 2) void gemm_qkv_8ph(const __hip_bfloat16* __restrict__ A,
                                                       const __hip_bfloat16* __restrict__ Bq,
                                                       const __hip_bfloat16* __restrict__ Bk,
                                                       const __hip_bfloat16* __restrict__ Bv,
                                                       __hip_bfloat16* __restrict__ Cq,
                                                       __hip_bfloat16* __restrict__ Ck,
                                                       __hip_bfloat16* __restrict__ Cvt,
                                                       const float* __restrict__ fc,
                                                       const float* __restrict__ fs) {
    __shared__ alignas(16) short smem[65536];  // 128 KiB: A 64K + B 64K, each 2buf x 2half x 16KB

    const int tid = threadIdx.x;
    const int wave = tid >> 6;
    const int lane = tid & 63;
    const int lane15 = lane & 15;
    const int quad = lane >> 4;
    const int wr = wave >> 2;      // wave row 0..1  (A half = wr)
    const int wc = wave & 3;       // wave col 0..3
    const int wc1 = wc & 1;
    const int hb = wc >> 1;        // B half consumed by this wave
    const int rsel = lane >> 3;                    // staging: row-within-chunk
    const int gsrc = ((lane & 7) ^ rsel) * 8;      // staging: pre-swizzled source granule

    const int which = blockIdx.x >> 3;
    const int n0 = (blockIdx.x & 7) * 256;
    const int m0 = blockIdx.y * 256;
    const __hip_bfloat16* Bt = (which == 0) ? Bq : (which == 1) ? Bk : Bv;

    short8 af[8][2];
    short8 bfr[4][2];
    f32x4 acc[8][4];

    // prologue: all of K-tile 0 into buf0 (oldest 8 loads), then A halves of K-tile 1 into buf1.
    STAGE_A8(0, 0, 0);
    STAGE_B8(0, 0, 0);
    STAGE_A8(0, 1, 0);
    STAGE_B8(0, 1, 0);
    STAGE_A8(1, 0, 1);
    STAGE_A8(1, 1, 1);
#pragma unroll
    for (int i = 0; i < 8; ++i)
#pragma unroll
        for (int j = 0; j < 4; ++j)
            acc[i][j] = {0.f, 0.f, 0.f, 0.f};
    WAIT_VM(4);   // K-tile 0 resident; A(1) still in flight
    BARRIER;

#pragma unroll 1
    for (int g = 0; g < NKT; g += 2) {
        GROUP(g, 0, 1);
        GROUP(g + 1, 1, 0);
    }

    // epilogue: acc[mt][nt][i] -> row = m0 + wr*128 + mt*16 + quad*4 + i,
    //                             col = n0 + wc*64 + nt*16 + lane15
    if (which < 2) {
        __hip_bfloat16* C = (which == 0) ? Cq : Ck;
#pragma unroll
        for (int mt = 0; mt < 8; ++mt)
#pragma unroll
            for (int nt = 0; nt < 4; ++nt) {
                int col = n0 + wc * 64 + nt * 16 + lane15;
                int j = (col & 127) >> 1;
                bool odd = col & 1;
#pragma unroll
                for (int i = 0; i < 4; ++i) {
                    int row = m0 + wr * 128 + mt * 16 + quad * 4 + i;
                    float v = acc[mt][nt][i];
                    float p = __shfl_xor(v, 1, 64);
                    float c = fc[row * 64 + j];
                    float sn = fs[row * 64 + j];
                    float r = odd ? (p * sn + v * c) : (v * c - p * sn);
                    C[(size_t)row * DMODEL + col] = f2bf(r);
                }
            }
    } else {
#pragma unroll
        for (int mt = 0; mt < 8; ++mt) {
            int rowbase = m0 + wr * 128 + mt * 16 + quad * 4;
#pragma unroll
            for (int nt = 0; nt < 4; ++nt) {
                int col = n0 + wc * 64 + nt * 16 + lane15;
                short4v pk;
                pk.x = bfs(acc[mt][nt][0]);
                pk.y = bfs(acc[mt][nt][1]);
                pk.z = bfs(acc[mt][nt][2]);
                pk.w = bfs(acc[mt][nt][3]);
                *(short4v*)((short*)Cvt + (size_t)col * S_LEN + rowbase) = pk;
            }
        }
    }
}

// ---------------- final GEMM: out(f32) = A * Bt^T, 128x64 tiles, K-pair staging ----------------
__global__ __launch_bounds__(256) void gemm_out(const __hip_bfloat16* __restrict__ A,
                                                const __hip_bfloat16* __restrict__ Bt,
                                                float* __restrict__ C) {
    __shared__ alignas(16) __hip_bfloat16 As[2][128 * 32];
    __shared__ alignas(16) __hip_bfloat16 Bs[2][64 * 32];
    const int tid = threadIdx.x;
    const int wave = tid >> 6;
    const int lane = tid & 63;
    const int lane15 = lane & 15;
    const int quad = lane >> 4;
    const int m0 = blockIdx.y * 128;
    const int n0 = blockIdx.x * 64;
    const int wm = (wave >> 1) * 64;
    const int wn = (wave & 1) * 32;
    f32x4 acc[4][2];
    for (int i = 0; i < 4; ++i)
        for (int j = 0; j < 2; ++j)
            acc[i][j] = {0.f, 0.f, 0.f, 0.f};
    const int rA = lane >> 2;
    const int cA = (lane & 3) * 8;
    for (int k0 = 0; k0 < DMODEL; k0 += 64) {
        __syncthreads();
        for (int h = 0; h < 2; ++h) {
            int kk = k0 + h * 32;
            for (int c = 0; c < 3; ++c) {
                int chunk = wave * 3 + c;
                if (chunk < 8) {
                    int r = chunk * 16 + rA;
                    stage16(A + (size_t)(m0 + r) * DMODEL + kk + cA, As[h] + chunk * 512, lane);
                } else {
                    int r = (chunk - 8) * 16 + rA;
                    stage16(Bt + (size_t)(n0 + r) * DMODEL + kk + cA, Bs[h] + (chunk - 8) * 512, lane);
                }
            }
        }
#if HAVE_ASYNC_LDS
        asm volatile("s_waitcnt vmcnt(0)" ::: "memory");
#endif
        __syncthreads();
        for (int h = 0; h < 2; ++h) {
            short8 af[4], bfr[2];
            for (int mt = 0; mt < 4; ++mt)
                af[mt] = *(const short8*)(As[h] + (wm + mt * 16 + lane15) * 32 + quad * 8);
            for (int nt = 0; nt < 2; ++nt)
                bfr[nt] = *(const short8*)(Bs[h] + (wn + nt * 16 + lane15) * 32 + quad * 8);
            for (int mt = 0; mt < 4; ++mt)
                for (int nt = 0; nt < 2; ++nt)
                    acc[mt][nt] = __builtin_amdgcn_mfma_f32_16x16x32_bf16(af[mt], bfr[nt], acc[mt][nt], 0, 0, 0);
        }
    }
    for (int mt = 0; mt < 4; ++mt)
        for (int nt = 0; nt < 2; ++nt)
            for (int i = 0; i < 4; ++i) {
                int row = m0 + wm + mt * 16 + quad * 4 + i;
                int col = n0 + wn + nt * 16 + lane15;
                C[(size_t)row * DMODEL + col] = acc[mt][nt][i];
            }
}

// ---------------- flash attention (LDS-shared K/V, fixed-base softmax) ----------------
__global__ __launch_bounds__(256) void flash_attn(const __hip_bfloat16* __restrict__ Q,
                                                  const __hip_bfloat16* __restrict__ Kb,
                                                  const __hip_bfloat16* __restrict__ Vt,
                                                  __hip_bfloat16* __restrict__ O) {
    __shared__ alignas(16) short Ks[32][136];
    __shared__ alignas(16) short Vs[128][40];
    __shared__ alignas(16) short Pl[4][16][40];
    const int tid = threadIdx.x;
    const int wave = tid >> 6;
    const int lane = tid & 63;
    const int lane15 = lane & 15;
    const int quad = lane >> 4;
    const int bx = blockIdx.x;                   // 0..511
    const int u = bx & 255;
    const int head = u & 15;
    const int qp = u >> 4;
    const int qb = (bx < 256) ? (31 - qp) : qp;  // complementary pairing
    const int qbase = qb * 64;
    const int q0w = qbase + wave * 16;
    const int nkt = 2 * qb + 2;
    const float K1 = 0.08838834764831845f * (1.0f / 25.0f);

    const __hip_bfloat16* Qh = Q + (size_t)q0w * DMODEL + head * HEAD_DIM;
    short8 qf[4];
    for (int kk = 0; kk < 4; ++kk)
        qf[kk] = *(const short8*)(Qh + (size_t)lane15 * DMODEL + kk * 32 + quad * 8);

    f32x4 acc[8];
    for (int i = 0; i < 8; ++i) acc[i] = {0.f, 0.f, 0.f, 0.f};
    float lpart[4] = {0.f, 0.f, 0.f, 0.f};

    const int krow = tid >> 3, kcol = (tid & 7) * 16;
    const int vrow = tid >> 1, vcol = (tid & 1) * 16;
    const __hip_bfloat16* Kg = Kb + (size_t)krow * DMODEL + head * HEAD_DIM + kcol;
    const __hip_bfloat16* Vg = Vt + (size_t)(head * HEAD_DIM + vrow) * S_LEN + vcol;

    short8 gk0 = *(const short8*)(Kg);
    short8 gk1 = *(const short8*)(Kg + 8);
    short8 gv0 = *(const short8*)(Vg);
    short8 gv1 = *(const short8*)(Vg + 8);

    for (int kt = 0; kt < nkt; ++kt) {
        const int kb = kt * 32;
        __syncthreads();
        *(short8*)&Ks[krow][kcol] = gk0;
        *(short8*)&Ks[krow][kcol + 8] = gk1;
        *(short8*)&Vs[vrow][vcol] = gv0;
        *(short8*)&Vs[vrow][vcol + 8] = gv1;
        __syncthreads();

        if (kt + 1 < nkt) {
            const __hip_bfloat16* Kg2 = Kg + (size_t)(kb + 32) * DMODEL;
            const __hip_bfloat16* Vg2 = Vg + kb + 32;
            gk0 = *(const short8*)(Kg2);
            gk1 = *(const short8*)(Kg2 + 8);
            gv0 = *(const short8*)(Vg2);
            gv1 = *(const short8*)(Vg2 + 8);
        }

        if (kb <= q0w + 15) {
            f32x4 sc[2];
            sc[0] = {0.f, 0.f, 0.f, 0.f};
            sc[1] = {0.f, 0.f, 0.f, 0.f};
            for (int c = 0; c < 2; ++c)
                for (int kk = 0; kk < 4; ++kk) {
                    short8 kf = *(const short8*)&Ks[c * 16 + lane15][kk * 32 + quad * 8];
                    sc[c] = __builtin_amdgcn_mfma_f32_16x16x32_bf16(qf[kk], kf, sc[c], 0, 0, 0);
                }

            const bool masked = (kb + 31 > q0w);
            const int key0 = kb + lane15;
            const int key1 = kb + 16 + lane15;
            for (int i = 0; i < 4; ++i) {
                float e0 = __expf(sc[0][i] * K1);
                float e1 = __expf(sc[1][i] * K1);
                float c0 = __builtin_fmaf(-100.0f, __builtin_amdgcn_rcpf(e0 + 1.0f), 40.0f);
                float c1 = __builtin_fmaf(-100.0f, __builtin_amdgcn_rcpf(e1 + 1.0f), 40.0f);
                float p0 = __expf(c0);
                float p1 = __expf(c1);
                if (masked) {
                    int q = q0w + quad * 4 + i;
                    if (key0 > q) p0 = 0.f;
                    if (key1 > q) p1 = 0.f;
                }
                short b0 = bfs(p0), b1 = bfs(p1);
                lpart[i] += sbf(b0) + sbf(b1);
                Pl[wave][quad * 4 + i][lane15] = b0;
                Pl[wave][quad * 4 + i][16 + lane15] = b1;
            }
            asm volatile("s_waitcnt lgkmcnt(0)" ::: "memory");
            short8 pf = *(const short8*)&Pl[wave][lane15][quad * 8];
            asm volatile("" ::: "memory");
            for (int nt = 0; nt < 8; ++nt) {
                short8 vf = *(const short8*)&Vs[nt * 16 + lane15][quad * 8];
                acc[nt] = __builtin_amdgcn_mfma_f32_16x16x32_bf16(pf, vf, acc[nt], 0, 0, 0);
            }
        }
    }

    for (int i = 0; i < 4; ++i) {
        float l = lpart[i];
        l += __shfl_xor(l, 1, 64);
        l += __shfl_xor(l, 2, 64);
        l += __shfl_xor(l, 4, 64);
        l += __shfl_xor(l, 8, 64);
        float inv = 1.0f / l;
        int row = q0w + quad * 4 + i;
        for (int nt = 0; nt < 8; ++nt) {
            int col = head * HEAD_DIM + nt * 16 + lane15;
            O[(size_t)row * DMODEL + col] = f2bf(acc[nt][i] * inv);
        }
    }
}

extern "C" void kernel_launch(void* const* d_in, const int* in_sizes, int n_in,
                              void* d_out, int out_size, void* d_ws, size_t ws_size,
                              hipStream_t stream) {
    const float* x  = (const float*)d_in[0];
    const float* wq = (const float*)d_in[1];
    const float* wk = (const float*)d_in[2];
    const float* wv = (const float*)d_in[3];
    const float* wo = (const float*)d_in[4];
    const float* fc = (const float*)d_in[5];
    const float* fs = (const float*)d_in[6];
    float* out = (float*)d_out;

    char* ws = (char*)d_ws;
    const size_t MB8 = (size_t)2048 * 2048 * sizeof(__hip_bfloat16);
    __hip_bfloat16* wq_t = (__hip_bfloat16*)(ws + 0 * MB8);
    __hip_bfloat16* wk_t = (__hip_bfloat16*)(ws + 1 * MB8);
    __hip_bfloat16* wv_t = (__hip_bfloat16*)(ws + 2 * MB8);
    __hip_bfloat16* wo_t = (__hip_bfloat16*)(ws + 3 * MB8);
    __hip_bfloat16* s4   = (__hip_bfloat16*)(ws + 4 * MB8);
    __hip_bfloat16* s5   = (__hip_bfloat16*)(ws + 5 * MB8);
    __hip_bfloat16* s6   = (__hip_bfloat16*)(ws + 6 * MB8);
    __hip_bfloat16* x_bf = (__hip_bfloat16*)d_out;  // dead before final GEMM writes d_out

    prep<<<dim3(32, 32, 5), 256, 0, stream>>>(x, wq, wk, wv, wo, x_bf, wq_t, wk_t, wv_t, wo_t);

    // Fused QKV: Q->s4 (roped), K->s5 (roped), V^T->s6. No reduce pass.
    gemm_qkv_8ph<<<dim3(24, 8), 512, 0, stream>>>(x_bf, wq_t, wk_t, wv_t, s4, s5, s6, fc, fs);

    // attn -> wq_t (dead after QKV GEMM)
    flash_attn<<<512, 256, 0, stream>>>(s4, s5, s6, wq_t);
    gemm_out<<<dim3(32, 16), 256, 0, stream>>>(wq_t, wo_t, out);
}

// Round 4
// 277.706 us; speedup vs baseline: 1.1038x; 1.0534x over previous
//
#include <hip/hip_runtime.h>
#include <hip/hip_bf16.h>

typedef __attribute__((ext_vector_type(8))) short short8;
typedef __attribute__((ext_vector_type(4))) short short4v;
typedef __attribute__((ext_vector_type(4))) float f32x4;
typedef __attribute__((ext_vector_type(4))) float float4v;

#define S_LEN 2048
#define DMODEL 2048
#define N_HEADS 16
#define HEAD_DIM 128
#define NKT 32  // K-tiles of 64 across DMODEL

__device__ __forceinline__ float bf2f(__hip_bfloat16 b) { return __bfloat162float(b); }
__device__ __forceinline__ __hip_bfloat16 f2bf(float f) { return __float2bfloat16(f); }
__device__ __forceinline__ short bfs(float f) {
    union { __hip_bfloat16 b; short s; } x; x.b = __float2bfloat16(f); return x.s;
}
__device__ __forceinline__ float sbf(short s) {
    union { short s; __hip_bfloat16 b; } x; x.s = s; return __bfloat162float(x.b);
}

#if __has_builtin(__builtin_amdgcn_global_load_lds)
#define HAVE_ASYNC_LDS 1
#else
#define HAVE_ASYNC_LDS 0
#endif

// Stage 16B per lane into LDS. ldsbase must be wave-uniform; HW scatters lane i at base + 16*i.
__device__ __forceinline__ void stage16(const __hip_bfloat16* g, __hip_bfloat16* ldsbase, int lane) {
#if HAVE_ASYNC_LDS
    __builtin_amdgcn_global_load_lds(
        (const __attribute__((address_space(1))) unsigned int*)g,
        (__attribute__((address_space(3))) unsigned int*)ldsbase,
        16, 0, 0);
#else
    *(short8*)((char*)ldsbase + lane * 16) = *(const short8*)g;
#endif
}

// ---------------- prep: 4 weight transposes (f32->bf16, vectorized) + x conversion ----------------
// grid (32,32,5), 256 threads. z<4: 64x64 transpose tiles; z==4: x convert (16 elems/thread).
__global__ __launch_bounds__(256) void prep(const float* __restrict__ x,
                                            const float* __restrict__ w0,
                                            const float* __restrict__ w1,
                                            const float* __restrict__ w2,
                                            const float* __restrict__ w3,
                                            __hip_bfloat16* __restrict__ xb,
                                            __hip_bfloat16* __restrict__ o0,
                                            __hip_bfloat16* __restrict__ o1,
                                            __hip_bfloat16* __restrict__ o2,
                                            __hip_bfloat16* __restrict__ o3) {
    const int z = blockIdx.z;
    const int tid = threadIdx.x;
    if (z == 4) {
        size_t base = (((size_t)blockIdx.y * 32 + blockIdx.x) * 256 + tid) * 16;
        for (int i = 0; i < 4; ++i) {
            float4v v = *(const float4v*)(x + base + i * 4);
            short4v p;
            p.x = bfs(v.x); p.y = bfs(v.y); p.z = bfs(v.z); p.w = bfs(v.w);
            *(short4v*)((short*)xb + base + i * 4) = p;
        }
        return;
    }
    const float* in = (z == 0) ? w0 : (z == 1) ? w1 : (z == 2) ? w2 : w3;
    __hip_bfloat16* out = (z == 0) ? o0 : (z == 1) ? o1 : (z == 2) ? o2 : o3;
    __shared__ short tile[64][68];
    const int bx = blockIdx.x * 64;
    const int by = blockIdx.y * 64;
    const int c4 = (tid & 15) * 4;
    for (int rr = 0; rr < 4; ++rr) {
        int r = (tid >> 4) + rr * 16;
        float4v v = *(const float4v*)(in + (size_t)(by + r) * DMODEL + bx + c4);
        short4v p;
        p.x = bfs(v.x); p.y = bfs(v.y); p.z = bfs(v.z); p.w = bfs(v.w);
        *(short4v*)&tile[r][c4] = p;
    }
    __syncthreads();
    const int oc = tid >> 2;
    const int s0 = (tid & 3) * 16;
    short8 a, b;
    for (int i = 0; i < 8; ++i) ((short*)&a)[i] = tile[s0 + i][oc];
    for (int i = 0; i < 8; ++i) ((short*)&b)[i] = tile[s0 + 8 + i][oc];
    *(short8*)((short*)out + (size_t)(bx + oc) * DMODEL + by + s0) = a;
    *(short8*)((short*)out + (size_t)(bx + oc) * DMODEL + by + s0 + 8) = b;
}

// ---------------- 256x256 QKV GEMM, 2-barrier groups with counted waits ----------------

#define CFENCE asm volatile("" ::: "memory")
#define BARRIER do { CFENCE; __builtin_amdgcn_s_barrier(); CFENCE; } while (0)
#define WAIT_LGKM0 asm volatile("s_waitcnt lgkmcnt(0)" ::: "memory")
#define WAIT_VM(n) asm volatile("s_waitcnt vmcnt(" #n ")" ::: "memory")

#define STAGE_A8(buf, half, kt) do {                                                        \
    const __hip_bfloat16* gpA_ = A + (size_t)(m0 + (half) * 128 + wave * 16 + rsel) * DMODEL \
                                 + (kt) * 64 + gsrc;                                        \
    __hip_bfloat16* lpA_ = (__hip_bfloat16*)(smem + ((buf) * 2 + (half)) * 8192 + wave * 1024); \
    stage16(gpA_, lpA_, lane);                                                              \
    stage16(gpA_ + (size_t)8 * DMODEL, lpA_ + 512, lane);                                   \
} while (0)

#define STAGE_B8(buf, half, kt) do {                                                        \
    const __hip_bfloat16* gpB_ = Bt + (size_t)(n0 + (half) * 128 + wave * 16 + rsel) * DMODEL \
                                 + (kt) * 64 + gsrc;                                        \
    __hip_bfloat16* lpB_ = (__hip_bfloat16*)(smem + 32768 + ((buf) * 2 + (half)) * 8192 + wave * 1024); \
    stage16(gpB_, lpB_, lane);                                                              \
    stage16(gpB_ + (size_t)8 * DMODEL, lpB_ + 512, lane);                                   \
} while (0)

#define LDA_ALL(buf) do {                                                                   \
    const char* ab_ = (const char*)(smem + ((buf) * 2 + wr) * 8192);                        \
    _Pragma("unroll")                                                                       \
    for (int mt_ = 0; mt_ < 8; ++mt_) {                                                     \
        const int rowL_ = mt_ * 16 + lane15;                                                \
        const int r7_ = rowL_ & 7;                                                          \
        af[mt_][0] = *(const short8*)(ab_ + rowL_ * 128 + ((quad ^ r7_) * 16));             \
        af[mt_][1] = *(const short8*)(ab_ + rowL_ * 128 + (((4 + quad) ^ r7_) * 16));       \
    }                                                                                       \
} while (0)

#define LDB_ALL(buf) do {                                                                   \
    const char* bb_ = (const char*)(smem + 32768 + ((buf) * 2 + hb) * 8192);                \
    _Pragma("unroll")                                                                       \
    for (int nt_ = 0; nt_ < 4; ++nt_) {                                                     \
        const int rowL_ = wc1 * 64 + nt_ * 16 + lane15;                                     \
        const int r7_ = rowL_ & 7;                                                          \
        bfr[nt_][0] = *(const short8*)(bb_ + rowL_ * 128 + ((quad ^ r7_) * 16));            \
        bfr[nt_][1] = *(const short8*)(bb_ + rowL_ * 128 + (((4 + quad) ^ r7_) * 16));      \
    }                                                                                       \
} while (0)

#define MFMAQ(mb, nb) do {                                                                  \
    _Pragma("unroll")                                                                       \
    for (int mt_ = 0; mt_ < 4; ++mt_) {                                                     \
        _Pragma("unroll")                                                                   \
        for (int nt_ = 0; nt_ < 2; ++nt_) {                                                 \
            acc[(mb) + mt_][(nb) + nt_] = __builtin_amdgcn_mfma_f32_16x16x32_bf16(          \
                af[(mb) + mt_][0], bfr[(nb) + nt_][0], acc[(mb) + mt_][(nb) + nt_], 0, 0, 0); \
            acc[(mb) + mt_][(nb) + nt_] = __builtin_amdgcn_mfma_f32_16x16x32_bf16(          \
                af[(mb) + mt_][1], bfr[(nb) + nt_][1], acc[(mb) + mt_][(nb) + nt_], 0, 0, 0); \
        }                                                                                   \
    }                                                                                       \
} while (0)

#define GROUP(g, cur, nxt) do {                                                             \
    const int g_ = (g);                                                                     \
    const bool stB_ = (g_ + 1 < NKT);                                                       \
    const bool stA_ = (g_ + 2 < NKT);                                                       \
    LDA_ALL(cur);                                                                           \
    LDB_ALL(cur);                                                                           \
    if (stB_) { STAGE_B8(nxt, 0, g_ + 1); STAGE_B8(nxt, 1, g_ + 1); }                       \
    __builtin_amdgcn_s_setprio(1);                                                          \
    MFMAQ(0, 0); MFMAQ(4, 0);                                                               \
    __builtin_amdgcn_s_setprio(0);                                                          \
    WAIT_LGKM0;                                                                             \
    BARRIER;                                                                                \
    if (stA_) { STAGE_A8(cur, 0, g_ + 2); STAGE_A8(cur, 1, g_ + 2); }                       \
    __builtin_amdgcn_s_setprio(1);                                                          \
    MFMAQ(0, 2); MFMAQ(4, 2);                                                               \
    __builtin_amdgcn_s_setprio(0);                                                          \
    if (stA_) { WAIT_VM(4); }                                                               \
    else if (stB_) { WAIT_VM(0); }                                                          \
    BARRIER;                                                                                \
} while (0)

__global__ __launch_bounds__(512, 2) void gemm_qkv_8ph(const __hip_bfloat16* __restrict__ A,
                                                       const __hip_bfloat16* __restrict__ Bq,
                                                       const __hip_bfloat16* __restrict__ Bk,
                                                       const __hip_bfloat16* __restrict__ Bv,
                                                       __hip_bfloat16* __restrict__ Cq,
                                                       __hip_bfloat16* __restrict__ Ck,
                                                       __hip_bfloat16* __restrict__ Cvt,
                                                       const float* __restrict__ fc,
                                                       const float* __restrict__ fs) {
    __shared__ alignas(16) short smem[65536];  // 128 KiB: A 64K + B 64K, each 2buf x 2half x 16KB

    const int tid = threadIdx.x;
    const int wave = tid >> 6;
    const int lane = tid & 63;
    const int lane15 = lane & 15;
    const int quad = lane >> 4;
    const int wr = wave >> 2;
    const int wc = wave & 3;
    const int wc1 = wc & 1;
    const int hb = wc >> 1;
    const int rsel = lane >> 3;
    const int gsrc = ((lane & 7) ^ rsel) * 8;

    const int which = blockIdx.x >> 3;
    const int n0 = (blockIdx.x & 7) * 256;
    const int m0 = blockIdx.y * 256;
    const __hip_bfloat16* Bt = (which == 0) ? Bq : (which == 1) ? Bk : Bv;

    short8 af[8][2];
    short8 bfr[4][2];
    f32x4 acc[8][4];

    STAGE_A8(0, 0, 0);
    STAGE_B8(0, 0, 0);
    STAGE_A8(0, 1, 0);
    STAGE_B8(0, 1, 0);
    STAGE_A8(1, 0, 1);
    STAGE_A8(1, 1, 1);
#pragma unroll
    for (int i = 0; i < 8; ++i)
#pragma unroll
        for (int j = 0; j < 4; ++j)
            acc[i][j] = {0.f, 0.f, 0.f, 0.f};
    WAIT_VM(4);
    BARRIER;

#pragma unroll 1
    for (int g = 0; g < NKT; g += 2) {
        GROUP(g, 0, 1);
        GROUP(g + 1, 1, 0);
    }

    if (which < 2) {
        __hip_bfloat16* C = (which == 0) ? Cq : Ck;
#pragma unroll
        for (int mt = 0; mt < 8; ++mt)
#pragma unroll
            for (int nt = 0; nt < 4; ++nt) {
                int col = n0 + wc * 64 + nt * 16 + lane15;
                int j = (col & 127) >> 1;
                bool odd = col & 1;
#pragma unroll
                for (int i = 0; i < 4; ++i) {
                    int row = m0 + wr * 128 + mt * 16 + quad * 4 + i;
                    float v = acc[mt][nt][i];
                    float p = __shfl_xor(v, 1, 64);
                    float c = fc[row * 64 + j];
                    float sn = fs[row * 64 + j];
                    float r = odd ? (p * sn + v * c) : (v * c - p * sn);
                    C[(size_t)row * DMODEL + col] = f2bf(r);
                }
            }
    } else {
#pragma unroll
        for (int mt = 0; mt < 8; ++mt) {
            int rowbase = m0 + wr * 128 + mt * 16 + quad * 4;
#pragma unroll
            for (int nt = 0; nt < 4; ++nt) {
                int col = n0 + wc * 64 + nt * 16 + lane15;
                short4v pk;
                pk.x = bfs(acc[mt][nt][0]);
                pk.y = bfs(acc[mt][nt][1]);
                pk.z = bfs(acc[mt][nt][2]);
                pk.w = bfs(acc[mt][nt][3]);
                *(short4v*)((short*)Cvt + (size_t)col * S_LEN + rowbase) = pk;
            }
        }
    }
}

// ---------------- final GEMM: out(f32) = A * Bt^T, 128x64 tiles, K-pair staging ----------------
__global__ __launch_bounds__(256) void gemm_out(const __hip_bfloat16* __restrict__ A,
                                                const __hip_bfloat16* __restrict__ Bt,
                                                float* __restrict__ C) {
    __shared__ alignas(16) __hip_bfloat16 As[2][128 * 32];
    __shared__ alignas(16) __hip_bfloat16 Bs[2][64 * 32];
    const int tid = threadIdx.x;
    const int wave = tid >> 6;
    const int lane = tid & 63;
    const int lane15 = lane & 15;
    const int quad = lane >> 4;
    const int m0 = blockIdx.y * 128;
    const int n0 = blockIdx.x * 64;
    const int wm = (wave >> 1) * 64;
    const int wn = (wave & 1) * 32;
    f32x4 acc[4][2];
    for (int i = 0; i < 4; ++i)
        for (int j = 0; j < 2; ++j)
            acc[i][j] = {0.f, 0.f, 0.f, 0.f};
    const int rA = lane >> 2;
    const int cA = (lane & 3) * 8;
    for (int k0 = 0; k0 < DMODEL; k0 += 64) {
        __syncthreads();
        for (int h = 0; h < 2; ++h) {
            int kk = k0 + h * 32;
            for (int c = 0; c < 3; ++c) {
                int chunk = wave * 3 + c;
                if (chunk < 8) {
                    int r = chunk * 16 + rA;
                    stage16(A + (size_t)(m0 + r) * DMODEL + kk + cA, As[h] + chunk * 512, lane);
                } else {
                    int r = (chunk - 8) * 16 + rA;
                    stage16(Bt + (size_t)(n0 + r) * DMODEL + kk + cA, Bs[h] + (chunk - 8) * 512, lane);
                }
            }
        }
#if HAVE_ASYNC_LDS
        asm volatile("s_waitcnt vmcnt(0)" ::: "memory");
#endif
        __syncthreads();
        for (int h = 0; h < 2; ++h) {
            short8 af[4], bfr[2];
            for (int mt = 0; mt < 4; ++mt)
                af[mt] = *(const short8*)(As[h] + (wm + mt * 16 + lane15) * 32 + quad * 8);
            for (int nt = 0; nt < 2; ++nt)
                bfr[nt] = *(const short8*)(Bs[h] + (wn + nt * 16 + lane15) * 32 + quad * 8);
            for (int mt = 0; mt < 4; ++mt)
                for (int nt = 0; nt < 2; ++nt)
                    acc[mt][nt] = __builtin_amdgcn_mfma_f32_16x16x32_bf16(af[mt], bfr[nt], acc[mt][nt], 0, 0, 0);
        }
    }
    for (int mt = 0; mt < 4; ++mt)
        for (int nt = 0; nt < 2; ++nt)
            for (int i = 0; i < 4; ++i) {
                int row = m0 + wm + mt * 16 + quad * 4 + i;
                int col = n0 + wn + nt * 16 + lane15;
                C[(size_t)row * DMODEL + col] = acc[mt][nt][i];
            }
}

// ---------------- flash attention, split-KV x2 (fixed-base softmax => partials add linearly) ----
// grid 1024: chunk = bx>>9; within 512: same complementary pairing as before.
// Chunk 0: key-tiles [0, qb+1); chunk 1: [qb+1, 2qb+2)  (equal work, disjoint staging).
// Writes f32 numerator + per-row denominators; attn_combine normalizes.
__global__ __launch_bounds__(256) void flash_attn(const __hip_bfloat16* __restrict__ Q,
                                                  const __hip_bfloat16* __restrict__ Kb,
                                                  const __hip_bfloat16* __restrict__ Vt,
                                                  float* __restrict__ N0,
                                                  float* __restrict__ N1,
                                                  float* __restrict__ L0,
                                                  float* __restrict__ L1) {
    __shared__ alignas(16) short Ks[32][136];
    __shared__ alignas(16) short Vs[128][40];
    __shared__ alignas(16) short Pl[4][16][40];
    const int tid = threadIdx.x;
    const int wave = tid >> 6;
    const int lane = tid & 63;
    const int lane15 = lane & 15;
    const int quad = lane >> 4;
    const int bx = blockIdx.x;                   // 0..1023
    const int chunk = bx >> 9;
    const int bxl = bx & 511;
    const int u = bxl & 255;
    const int head = u & 15;
    const int qp = u >> 4;
    const int qb = (bxl < 256) ? (31 - qp) : qp; // complementary pairing
    const int q0w = qb * 64 + wave * 16;
    const int k_lo = chunk ? (qb + 1) : 0;
    const int k_hi = chunk ? (2 * qb + 2) : (qb + 1);
    const float K1 = 0.08838834764831845f * (1.0f / 25.0f);

    float* __restrict__ Nw = chunk ? N1 : N0;
    float* __restrict__ Lw = chunk ? L1 : L0;

    const __hip_bfloat16* Qh = Q + (size_t)q0w * DMODEL + head * HEAD_DIM;
    short8 qf[4];
    for (int kk = 0; kk < 4; ++kk)
        qf[kk] = *(const short8*)(Qh + (size_t)lane15 * DMODEL + kk * 32 + quad * 8);

    f32x4 acc[8];
    for (int i = 0; i < 8; ++i) acc[i] = {0.f, 0.f, 0.f, 0.f};
    float lpart[4] = {0.f, 0.f, 0.f, 0.f};

    const int krow = tid >> 3, kcol = (tid & 7) * 16;
    const int vrow = tid >> 1, vcol = (tid & 1) * 16;
    const __hip_bfloat16* Kg = Kb + (size_t)krow * DMODEL + head * HEAD_DIM + kcol;
    const __hip_bfloat16* Vg = Vt + (size_t)(head * HEAD_DIM + vrow) * S_LEN + vcol;

    const int kb0 = k_lo * 32;
    short8 gk0 = *(const short8*)(Kg + (size_t)kb0 * DMODEL);
    short8 gk1 = *(const short8*)(Kg + (size_t)kb0 * DMODEL + 8);
    short8 gv0 = *(const short8*)(Vg + kb0);
    short8 gv1 = *(const short8*)(Vg + kb0 + 8);

    for (int kt = k_lo; kt < k_hi; ++kt) {
        const int kb = kt * 32;
        __syncthreads();
        *(short8*)&Ks[krow][kcol] = gk0;
        *(short8*)&Ks[krow][kcol + 8] = gk1;
        *(short8*)&Vs[vrow][vcol] = gv0;
        *(short8*)&Vs[vrow][vcol + 8] = gv1;
        __syncthreads();

        if (kt + 1 < k_hi) {
            const __hip_bfloat16* Kg2 = Kg + (size_t)(kb + 32) * DMODEL;
            const __hip_bfloat16* Vg2 = Vg + kb + 32;
            gk0 = *(const short8*)(Kg2);
            gk1 = *(const short8*)(Kg2 + 8);
            gv0 = *(const short8*)(Vg2);
            gv1 = *(const short8*)(Vg2 + 8);
        }

        if (kb <= q0w + 15) {
            f32x4 sc[2];
            sc[0] = {0.f, 0.f, 0.f, 0.f};
            sc[1] = {0.f, 0.f, 0.f, 0.f};
            for (int c = 0; c < 2; ++c)
                for (int kk = 0; kk < 4; ++kk) {
                    short8 kf = *(const short8*)&Ks[c * 16 + lane15][kk * 32 + quad * 8];
                    sc[c] = __builtin_amdgcn_mfma_f32_16x16x32_bf16(qf[kk], kf, sc[c], 0, 0, 0);
                }

            const bool masked = (kb + 31 > q0w);
            const int key0 = kb + lane15;
            const int key1 = kb + 16 + lane15;
            for (int i = 0; i < 4; ++i) {
                float e0 = __expf(sc[0][i] * K1);
                float e1 = __expf(sc[1][i] * K1);
                float c0 = __builtin_fmaf(-100.0f, __builtin_amdgcn_rcpf(e0 + 1.0f), 40.0f);
                float c1 = __builtin_fmaf(-100.0f, __builtin_amdgcn_rcpf(e1 + 1.0f), 40.0f);
                float p0 = __expf(c0);
                float p1 = __expf(c1);
                if (masked) {
                    int q = q0w + quad * 4 + i;
                    if (key0 > q) p0 = 0.f;
                    if (key1 > q) p1 = 0.f;
                }
                short b0 = bfs(p0), b1 = bfs(p1);
                lpart[i] += sbf(b0) + sbf(b1);
                Pl[wave][quad * 4 + i][lane15] = b0;
                Pl[wave][quad * 4 + i][16 + lane15] = b1;
            }
            asm volatile("s_waitcnt lgkmcnt(0)" ::: "memory");
            short8 pf = *(const short8*)&Pl[wave][lane15][quad * 8];
            asm volatile("" ::: "memory");
            for (int nt = 0; nt < 8; ++nt) {
                short8 vf = *(const short8*)&Vs[nt * 16 + lane15][quad * 8];
                acc[nt] = __builtin_amdgcn_mfma_f32_16x16x32_bf16(pf, vf, acc[nt], 0, 0, 0);
            }
        }
    }

    // epilogue: write raw f32 numerator rows + per-row partial denominators
    for (int i = 0; i < 4; ++i) {
        float l = lpart[i];
        l += __shfl_xor(l, 1, 64);
        l += __shfl_xor(l, 2, 64);
        l += __shfl_xor(l, 4, 64);
        l += __shfl_xor(l, 8, 64);
        int row = q0w + quad * 4 + i;
        if (lane15 == 0) Lw[(head << 11) + row] = l;
        for (int nt = 0; nt < 8; ++nt) {
            int col = head * HEAD_DIM + nt * 16 + lane15;
            Nw[(size_t)row * DMODEL + col] = acc[nt][i];
        }
    }
}

// ---------------- combine: A_bf16 = (N0+N1) / (L0+L1) ----------------
// grid 2048, 256 threads, 8 floats/thread. Head is constant within each 8-elem group.
__global__ __launch_bounds__(256) void attn_combine(const float* __restrict__ N0,
                                                    const float* __restrict__ N1,
                                                    const float* __restrict__ L0,
                                                    const float* __restrict__ L1,
                                                    __hip_bfloat16* __restrict__ Aout) {
    size_t i0 = ((size_t)blockIdx.x * 256 + threadIdx.x) * 8;
    const int row = (int)(i0 >> 11);
    const int head = (int)((i0 >> 7) & 15);
    const float l = L0[(head << 11) + row] + L1[(head << 11) + row];
    const float inv = 1.0f / l;
    float4v a0 = *(const float4v*)(N0 + i0);
    float4v a1 = *(const float4v*)(N1 + i0);
    float4v b0 = *(const float4v*)(N0 + i0 + 4);
    float4v b1 = *(const float4v*)(N1 + i0 + 4);
    short8 o;
    ((short*)&o)[0] = bfs((a0.x + a1.x) * inv);
    ((short*)&o)[1] = bfs((a0.y + a1.y) * inv);
    ((short*)&o)[2] = bfs((a0.z + a1.z) * inv);
    ((short*)&o)[3] = bfs((a0.w + a1.w) * inv);
    ((short*)&o)[4] = bfs((b0.x + b1.x) * inv);
    ((short*)&o)[5] = bfs((b0.y + b1.y) * inv);
    ((short*)&o)[6] = bfs((b0.z + b1.z) * inv);
    ((short*)&o)[7] = bfs((b0.w + b1.w) * inv);
    *(short8*)((short*)Aout + i0) = o;
}

extern "C" void kernel_launch(void* const* d_in, const int* in_sizes, int n_in,
                              void* d_out, int out_size, void* d_ws, size_t ws_size,
                              hipStream_t stream) {
    const float* x  = (const float*)d_in[0];
    const float* wq = (const float*)d_in[1];
    const float* wk = (const float*)d_in[2];
    const float* wv = (const float*)d_in[3];
    const float* wo = (const float*)d_in[4];
    const float* fc = (const float*)d_in[5];
    const float* fs = (const float*)d_in[6];
    float* out = (float*)d_out;

    char* ws = (char*)d_ws;
    const size_t MB8 = (size_t)2048 * 2048 * sizeof(__hip_bfloat16);
    __hip_bfloat16* wq_t = (__hip_bfloat16*)(ws + 0 * MB8);
    __hip_bfloat16* wk_t = (__hip_bfloat16*)(ws + 1 * MB8);
    __hip_bfloat16* wv_t = (__hip_bfloat16*)(ws + 2 * MB8);
    __hip_bfloat16* wo_t = (__hip_bfloat16*)(ws + 3 * MB8);
    __hip_bfloat16* s4   = (__hip_bfloat16*)(ws + 4 * MB8);
    __hip_bfloat16* s5   = (__hip_bfloat16*)(ws + 5 * MB8);
    __hip_bfloat16* s6   = (__hip_bfloat16*)(ws + 6 * MB8);
    float* N1 = (float*)(ws + 7 * MB8);          // 16MB, spans slots 7-8
    float* L0 = (float*)(ws + 9 * MB8);          // 128KB
    float* L1 = L0 + 2048 * 16;                  // 128KB
    __hip_bfloat16* x_bf = (__hip_bfloat16*)d_out;  // dead before final GEMM writes d_out
    float* N0 = (float*)d_out;                   // chunk-0 numerator reuses d_out (dead window)

    prep<<<dim3(32, 32, 5), 256, 0, stream>>>(x, wq, wk, wv, wo, x_bf, wq_t, wk_t, wv_t, wo_t);

    // Fused QKV: Q->s4 (roped), K->s5 (roped), V^T->s6.
    gemm_qkv_8ph<<<dim3(24, 8), 512, 0, stream>>>(x_bf, wq_t, wk_t, wv_t, s4, s5, s6, fc, fs);

    // split-KV attention: chunk0 -> N0 (=d_out, free now), chunk1 -> N1
    flash_attn<<<1024, 256, 0, stream>>>(s4, s5, s6, N0, N1, L0, L1);

    // combine -> s4 (Q dead), then final GEMM s4 x wo_t -> out
    attn_combine<<<2048, 256, 0, stream>>>(N0, N1, L0, L1, s4);
    gemm_out<<<dim3(32, 16), 256, 0, stream>>>(s4, wo_t, out);
}